// Round 1
// baseline (198.380 us; speedup 1.0000x reference)
//
#include <hip/hip_runtime.h>
#include <hip/hip_bf16.h>
#include <stdint.h>

// ---- problem constants (B=2, T=2048, C=1024, H=16, hs=64) ----
#define BSZ   2
#define TT    2048
#define NH    16
#define HS    64
#define CC    1024
#define C3    3072
#define MT    4096            // B*T rows
#define E10   4.5399929762484854e-05f   // exp(-10)
#define SCL2  0.1803368801111204f       // 0.125 * log2(e)

typedef __bf16 bf16;
typedef __bf16 bf16x8 __attribute__((ext_vector_type(8)));
typedef float  f32x4  __attribute__((ext_vector_type(4)));
typedef short  s16x4  __attribute__((ext_vector_type(4)));

#define AS1 __attribute__((address_space(1)))
#define AS3 __attribute__((address_space(3)))

__device__ __forceinline__ void glds16(const bf16* g, bf16* l) {
    __builtin_amdgcn_global_load_lds((const AS1 void*)g, (AS3 void*)l, 16, 0, 0);
}

// =====================================================================
// Input dtype detector: flag=0 -> bf16 inputs, flag=1 -> fp32 inputs.
// =====================================================================
__global__ void detect_dtype(const uint16_t* __restrict__ x, int* __restrict__ flag) {
    __shared__ int cnt;
    if (threadIdx.x == 0) cnt = 0;
    __syncthreads();
    int local = 0;
    for (int i = threadIdx.x; i < 512; i += 256) {
        uint16_t u = x[i];
        int e = (u >> 7) & 0xFF;
        if (e >= 96 && e <= 159) local++;
    }
    atomicAdd(&cnt, local);
    __syncthreads();
    if (threadIdx.x == 0) *flag = (cnt >= 461) ? 0 : 1;
}

// fused fp32->bf16 converts for x / w_attn / w_proj (no-op when flag==0)
#define NX8  (MT * CC / 8)          // 524288
#define NWA8 (C3 * CC / 8)          // 393216
#define NWP8 (CC * CC / 8)          // 131072
__global__ __launch_bounds__(256)
void convert_all(const float* __restrict__ x, const float* __restrict__ wa,
                 const float* __restrict__ wp, bf16* __restrict__ xd,
                 bf16* __restrict__ wad, bf16* __restrict__ wpd,
                 const int* __restrict__ flag) {
    if (*flag == 0) return;
    long i = (long)blockIdx.x * 256 + threadIdx.x;
    const float* s; bf16* d; long off;
    if (i < NX8)             { s = x;  d = xd;  off = i; }
    else if (i < NX8 + NWA8) { s = wa; d = wad; off = i - NX8; }
    else                     { s = wp; d = wpd; off = i - NX8 - NWA8; }
    const float4* sp = reinterpret_cast<const float4*>(s) + off * 2;
    float4 a = sp[0], b = sp[1];
    bf16x8 r;
    r[0] = (bf16)a.x; r[1] = (bf16)a.y; r[2] = (bf16)a.z; r[3] = (bf16)a.w;
    r[4] = (bf16)b.x; r[5] = (bf16)b.y; r[6] = (bf16)b.z; r[7] = (bf16)b.w;
    reinterpret_cast<bf16x8*>(d)[off] = r;
}

// =====================================================================
// GEMM 128x128: C = A*B^T, dbuf single-barrier pipeline. Split store:
// col-blocks >= split_col write V directly in Vt layout (sigma-packed):
// tloc = mi*16+quad*4+r -> sigma(tloc) = quad*16+mi*4+r (r contiguous,
// 8B packed store). Kills the separate vtranspose pass.
// =====================================================================
__global__ __launch_bounds__(256)
void gemm_bt(const bf16* __restrict__ A0, const bf16* __restrict__ A1,
             const bf16* __restrict__ B0, const bf16* __restrict__ B1,
             void* __restrict__ Cmain, bf16* __restrict__ Cv,
             const int* __restrict__ flag,
             int M, int N, int K, int lda, int ldb, int ldc,
             int split_col, int cf32_dyn) {
    __shared__ bf16 As[2][128 * 32];
    __shared__ bf16 Bs[2][128 * 32];

    const int f = *flag;
    const bf16* A = f ? A1 : A0;
    const bf16* B = f ? B1 : B0;
    const int cf32 = cf32_dyn & f;

    const int tid  = threadIdx.x;
    const int lane = tid & 63;
    const int wave = tid >> 6;
    const int wm   = wave >> 1;
    const int wn   = wave & 1;
    const int quad = lane >> 4;
    const int l16  = lane & 15;

    const int row0 = blockIdx.y * 128;
    const int col0 = blockIdx.x * 128;

    const int srow = tid >> 2;
    const int skk  = (tid & 3) * 8;

    const bf16* Ap = A + (long)(row0 + srow) * lda + skk;
    const bf16* Bp = B + (long)(col0 + srow) * ldb + skk;

    auto stage = [&](int k0, int buf) {
        glds16(Ap + k0,                  &As[buf][wave * 512]);
        glds16(Ap + (long)64 * lda + k0, &As[buf][wave * 512 + 2048]);
        glds16(Bp + k0,                  &Bs[buf][wave * 512]);
        glds16(Bp + (long)64 * ldb + k0, &Bs[buf][wave * 512 + 2048]);
    };

    f32x4 acc[4][4] = {};
    stage(0, 0);

    for (int k0 = 0; k0 < K; k0 += 32) {
        const int buf = (k0 >> 5) & 1;
        __syncthreads();
        if (k0 + 32 < K) stage(k0 + 32, buf ^ 1);

        const bf16* Ac = As[buf];
        const bf16* Bc = Bs[buf];
        bf16x8 af[4], bfv[4];
#pragma unroll
        for (int mi = 0; mi < 4; ++mi)
            af[mi] = *reinterpret_cast<const bf16x8*>(&Ac[(wm * 64 + mi * 16 + l16) * 32 + quad * 8]);
#pragma unroll
        for (int ni = 0; ni < 4; ++ni)
            bfv[ni] = *reinterpret_cast<const bf16x8*>(&Bc[(wn * 64 + ni * 16 + l16) * 32 + quad * 8]);
#pragma unroll
        for (int mi = 0; mi < 4; ++mi)
#pragma unroll
            for (int ni = 0; ni < 4; ++ni)
                acc[mi][ni] = __builtin_amdgcn_mfma_f32_16x16x32_bf16(af[mi], bfv[ni], acc[mi][ni], 0, 0, 0);
    }

    if (split_col < 0 || col0 < split_col) {
        // main store (C/D layout: col=l16, row=quad*4+reg)
#pragma unroll
        for (int mi = 0; mi < 4; ++mi)
#pragma unroll
            for (int ni = 0; ni < 4; ++ni)
#pragma unroll
                for (int r = 0; r < 4; ++r) {
                    int row = row0 + wm * 64 + mi * 16 + quad * 4 + r;
                    int col = col0 + wn * 64 + ni * 16 + l16;
                    float v = acc[mi][ni][r];
                    if (cf32) ((float*)Cmain)[(long)row * ldc + col] = v;
                    else      ((bf16*)Cmain)[(long)row * ldc + col] = (bf16)v;
                }
    } else {
        // V store in Vt[bh][d][tc*64 + sigma(tloc)] layout
        const int h  = (col0 - split_col + wn * 64) >> 6;   // wave-uniform
        const int bq = row0 >> 11;
        const int tc = ((row0 & 2047) >> 6) + wm;
#pragma unroll
        for (int ni = 0; ni < 4; ++ni) {
            long vrow = (long)(bq * NH + h) * 64 + ni * 16 + l16;
#pragma unroll
            for (int mi = 0; mi < 4; ++mi) {
                bf16 outv[4];
#pragma unroll
                for (int r = 0; r < 4; ++r) outv[r] = (bf16)acc[mi][ni][r];
                *reinterpret_cast<uint2*>(&Cv[vrow * 2048 + tc * 64 + quad * 16 + mi * 4]) =
                    *reinterpret_cast<uint2*>(outv);
            }
        }
    }
}

// =====================================================================
// GEMM 128x64 (gemm2): grid 512 = 2 blocks/CU. acc[4][2].
// =====================================================================
__global__ __launch_bounds__(256)
void gemm_bt64(const bf16* __restrict__ A0, const bf16* __restrict__ A1,
               const bf16* __restrict__ B0, const bf16* __restrict__ B1,
               void* __restrict__ C, const int* __restrict__ flag,
               int M, int N, int K, int lda, int ldb, int ldc, int cf32_dyn) {
    __shared__ bf16 As[2][128 * 32];
    __shared__ bf16 Bs[2][64 * 32];

    const int f = *flag;
    const bf16* A = f ? A1 : A0;
    const bf16* B = f ? B1 : B0;
    const int cf32 = cf32_dyn & f;

    const int tid  = threadIdx.x;
    const int lane = tid & 63;
    const int wave = tid >> 6;
    const int wm   = wave >> 1;
    const int wn   = wave & 1;
    const int quad = lane >> 4;
    const int l16  = lane & 15;

    const int row0 = blockIdx.y * 128;
    const int col0 = blockIdx.x * 64;

    const int srow = tid >> 2;
    const int skk  = (tid & 3) * 8;

    const bf16* Ap = A + (long)(row0 + srow) * lda + skk;
    const bf16* Bp = B + (long)(col0 + srow) * ldb + skk;

    auto stage = [&](int k0, int buf) {
        glds16(Ap + k0,                  &As[buf][wave * 512]);
        glds16(Ap + (long)64 * lda + k0, &As[buf][wave * 512 + 2048]);
        glds16(Bp + k0,                  &Bs[buf][wave * 512]);
    };

    f32x4 acc[4][2] = {};
    stage(0, 0);

    for (int k0 = 0; k0 < K; k0 += 32) {
        const int buf = (k0 >> 5) & 1;
        __syncthreads();
        if (k0 + 32 < K) stage(k0 + 32, buf ^ 1);

        const bf16* Ac = As[buf];
        const bf16* Bc = Bs[buf];
        bf16x8 af[4], bfv[2];
#pragma unroll
        for (int mi = 0; mi < 4; ++mi)
            af[mi] = *reinterpret_cast<const bf16x8*>(&Ac[(wm * 64 + mi * 16 + l16) * 32 + quad * 8]);
#pragma unroll
        for (int ni = 0; ni < 2; ++ni)
            bfv[ni] = *reinterpret_cast<const bf16x8*>(&Bc[(wn * 32 + ni * 16 + l16) * 32 + quad * 8]);
#pragma unroll
        for (int mi = 0; mi < 4; ++mi)
#pragma unroll
            for (int ni = 0; ni < 2; ++ni)
                acc[mi][ni] = __builtin_amdgcn_mfma_f32_16x16x32_bf16(af[mi], bfv[ni], acc[mi][ni], 0, 0, 0);
    }

#pragma unroll
    for (int mi = 0; mi < 4; ++mi)
#pragma unroll
        for (int ni = 0; ni < 2; ++ni)
#pragma unroll
            for (int r = 0; r < 4; ++r) {
                int row = row0 + wm * 64 + mi * 16 + quad * 4 + r;
                int col = col0 + wn * 32 + ni * 16 + l16;
                float v = acc[mi][ni][r];
                if (cf32) ((float*)C)[(long)row * ldc + col] = v;
                else      ((bf16*)C)[(long)row * ldc + col] = (bf16)v;
            }
}

// =====================================================================
// Per-(bh,kt) V tile sums from Vt rows (sigma permutes within a tile ->
// sum invariant). 1024 blocks, coalesced 32B/thread.
// =====================================================================
__global__ __launch_bounds__(256)
void vtile2(const bf16* __restrict__ Vt, float* __restrict__ Vtile) {
    const int kt = blockIdx.x, bh = blockIdx.y;
    const int tid = threadIdx.x;
    const int d = tid >> 2, part = tid & 3;
    const bf16* p = Vt + ((long)bh * 64 + d) * 2048 + kt * 64 + part * 16;
    float s = 0.f;
#pragma unroll
    for (int i = 0; i < 2; ++i) {
        bf16x8 v = *reinterpret_cast<const bf16x8*>(p + i * 8);
#pragma unroll
        for (int j = 0; j < 8; ++j) s += (float)v[j];
    }
    s += __shfl_xor(s, 1, 64);
    s += __shfl_xor(s, 2, 64);
    if (part == 0) Vtile[((long)bh * 32 + kt) * 64 + d] = s;
}

// Suffix over 64-key tiles (tiny).
__global__ void vts_suffix(const float* __restrict__ Vtile, float* __restrict__ Vts) {
    const int bh = blockIdx.x, d = threadIdx.x;
    Vts[((long)bh * 33 + 32) * 64 + d] = 0.f;
    float acc = 0.f;
    for (int kt = 31; kt >= 0; --kt) {
        acc += Vtile[((long)bh * 32 + kt) * 64 + d];
        Vts[((long)bh * 33 + kt) * 64 + d] = acc;
    }
}

// =====================================================================
// Flash attention: transposed compute + glds16 swizzled staging + dbuf
// single-barrier pipeline + XCD-locality swizzle.
// v2: 128 q-rows/block (2 subgroups of 64), so every K/V LDS fragment
// read and every 16KB tile staging feeds 2x the MFMA work (attn is
// LDS-pipe-bound: 16 ds_read_b128/wave-tile vs ~90 MFMA cycles).
// Grid 512 (2 blocks/CU); chunk c paired with 15-c on the same CU so
// per-CU tile count is constant (34). Subgroup 0 ends at tile 2c+1
// (future tiles folded via Vts suffix as before), subgroup 1 at 2c+2.
// =====================================================================
__global__ __launch_bounds__(256, 2)
void attn(bf16* __restrict__ qk, const bf16* __restrict__ Vt,
          const float* __restrict__ Vts) {
    __shared__ bf16 Ks[2][64 * 64];
    __shared__ bf16 Vs[2][64 * 64];

    const int tid  = threadIdx.x;
    const int lane = tid & 63;
    const int wave = tid >> 6;
    const int quad = lane >> 4;
    const int l16  = lane & 15;

    const int f2   = blockIdx.x;            // 0..511
    const int xcd  = f2 & 7;
    const int slot = f2 >> 3;               // 0..63
    const int bh   = (slot & 3) * 8 + xcd;
    const int g    = slot >> 2;             // 0..15
    // blocks 0..255: chunks 15..8 (heavy, launched first);
    // blocks 256..511: chunks 0..7 -> CU pairing (c, 15-c), const work.
    const int chunk = (g < 8) ? (15 - g) : (g - 8);
    const int b = bh >> 4, h = bh & 15;
    const int q0 = chunk * 128;
    const long rbase = (long)b * TT;
    const int ktend = 2 * chunk + 2;        // tiles for subgroup 1

    // Q fragments for both 64-row subgroups (hoisted, in-register)
    bf16x8 qf[2][2];
#pragma unroll
    for (int s = 0; s < 2; ++s) {
        const bf16* qp = qk + (rbase + q0 + s * 64 + wave * 16 + l16) * 2048 + h * HS;
        qf[s][0] = *reinterpret_cast<const bf16x8*>(qp + quad * 8);
        qf[s][1] = *reinterpret_cast<const bf16x8*>(qp + 32 + quad * 8);
    }

    f32x4 O[2][4] = {};
    float lp[2] = {0.f, 0.f};

    const int rl  = lane >> 3;
    const int cs  = (lane & 7) ^ rl;
    const int row0dma = wave * 16 + rl;
    const bf16* kgb = qk + (rbase + row0dma) * 2048 + CC + h * HS + cs * 8;
    const bf16* vgb = Vt + ((long)(b * NH + h) * 64 + row0dma) * 2048 + cs * 8;
    const int sx = l16 & 7;

    auto stage = [&](int kt, int buf) {
        glds16(kgb + (long)(kt * 64) * 2048,     &Ks[buf][wave * 1024]);
        glds16(kgb + (long)(kt * 64 + 8) * 2048, &Ks[buf][wave * 1024 + 512]);
        glds16(vgb + kt * 64,                    &Vs[buf][wave * 1024]);
        glds16(vgb + 8 * 2048 + kt * 64,         &Vs[buf][wave * 1024 + 512]);
    };

    stage(0, 0);

    for (int kt = 0; kt < ktend; ++kt) {
        const int buf = kt & 1;
        __syncthreads();
        if (kt + 1 < ktend) stage(kt + 1, buf ^ 1);

        const bf16* Kc = Ks[buf];
        const bf16* Vc = Vs[buf];

        bf16x8 kf0[4], kf1[4];
#pragma unroll
        for (int gg = 0; gg < 4; ++gg) {
            const int krow = gg * 16 + l16;
            kf0[gg] = *reinterpret_cast<const bf16x8*>(&Kc[krow * 64 + ((quad ^ sx) * 8)]);
            kf1[gg] = *reinterpret_cast<const bf16x8*>(&Kc[krow * 64 + (((4 + quad) ^ sx) * 8)]);
        }
        s16x4 vf[4][4];
#pragma unroll
        for (int dg = 0; dg < 4; ++dg) {
            const int vrow = dg * 16 + l16;
            union { uint4 u; s16x4 s[2]; } ua, ub;
            ua.u = *reinterpret_cast<const uint4*>(&Vc[vrow * 64 + (((2 * quad) ^ sx) * 8)]);
            ub.u = *reinterpret_cast<const uint4*>(&Vc[vrow * 64 + (((2 * quad + 1) ^ sx) * 8)]);
            vf[dg][0] = ua.s[0]; vf[dg][1] = ua.s[1];
            vf[dg][2] = ub.s[0]; vf[dg][3] = ub.s[1];
        }

#pragma unroll
        for (int s = 0; s < 2; ++s) {
            // subgroup 0 stops one tile earlier (its last tile is fully
            // future-masked -> handled by the Vts suffix correction)
            if (s == 0 && kt == ktend - 1) continue;

            f32x4 S[4] = {};
            __builtin_amdgcn_s_setprio(1);
#pragma unroll
            for (int gg = 0; gg < 4; ++gg) {
                S[gg] = __builtin_amdgcn_mfma_f32_16x16x32_bf16(kf0[gg], qf[s][0], S[gg], 0, 0, 0);
                S[gg] = __builtin_amdgcn_mfma_f32_16x16x32_bf16(kf1[gg], qf[s][1], S[gg], 0, 0, 0);
            }
            __builtin_amdgcn_s_setprio(0);

            const bool dtile = (kt == ktend - 2 + s);
            const int ql = wave * 16 + l16;
            s16x4 pk[4];
#pragma unroll
            for (int gg = 0; gg < 4; ++gg) {
#pragma unroll
                for (int r = 0; r < 4; ++r) {
                    float p = __builtin_exp2f(S[gg][r] * SCL2);
                    if (dtile) {
                        int kl = gg * 16 + quad * 4 + r;
                        p = (kl > ql) ? E10 : p;
                    }
                    lp[s] += p;
                    union { bf16 b_; short s_; } u;
                    u.b_ = (bf16)p;
                    pk[gg][r] = u.s_;
                }
            }

            __builtin_amdgcn_s_setprio(1);
#pragma unroll
            for (int dg = 0; dg < 4; ++dg) {
                O[s][dg] = __builtin_amdgcn_mfma_f32_16x16x16bf16_1k(vf[dg][0], pk[0], O[s][dg], 0, 0, 0);
                O[s][dg] = __builtin_amdgcn_mfma_f32_16x16x16bf16_1k(vf[dg][1], pk[1], O[s][dg], 0, 0, 0);
                O[s][dg] = __builtin_amdgcn_mfma_f32_16x16x16bf16_1k(vf[dg][2], pk[2], O[s][dg], 0, 0, 0);
                O[s][dg] = __builtin_amdgcn_mfma_f32_16x16x16bf16_1k(vf[dg][3], pk[3], O[s][dg], 0, 0, 0);
            }
            __builtin_amdgcn_s_setprio(0);
        }
    }

#pragma unroll
    for (int s = 0; s < 2; ++s) {
        float lps = lp[s];
        lps += __shfl_xor(lps, 16, 64);
        lps += __shfl_xor(lps, 32, 64);

        const int kte = ktend - 1 + s;           // tiles computed for subgroup s
        const int nfut = TT - kte * 64;
        const float l = lps + (float)nfut * E10;
        const float invl = 1.0f / l;
        const float* vfp = Vts + ((long)(b * NH + h) * 33 + kte) * 64;

        bf16* yp = qk + (rbase + q0 + s * 64 + wave * 16 + l16) * 2048 + h * HS;
#pragma unroll
        for (int dg = 0; dg < 4; ++dg) {
            bf16 outv[4];
#pragma unroll
            for (int r = 0; r < 4; ++r) {
                float o = O[s][dg][r] + E10 * vfp[dg * 16 + quad * 4 + r];
                outv[r] = (bf16)(o * invl);
            }
            *reinterpret_cast<uint2*>(yp + dg * 16 + quad * 4) =
                *reinterpret_cast<uint2*>(outv);
        }
    }
}

// =====================================================================
extern "C" void kernel_launch(void* const* d_in, const int* in_sizes, int n_in,
                              void* d_out, int out_size, void* d_ws, size_t ws_size,
                              hipStream_t stream) {
    const void* x      = d_in[0];
    const void* w_attn = d_in[1];
    const void* w_proj = d_in[2];

    // ws (~27.8 MB): qk | Vt | flag | Vts | wp_cvt | Vtile
    char* ws = (char*)d_ws;
    bf16*  qk     = (bf16*)ws;                                    // 16,777,216 B
    bf16*  Vt     = (bf16*)(ws + (size_t)MT * 2048 * 2);          //  8,388,608 B
    char*  p2     = ws + (size_t)MT * 2048 * 2 + (size_t)32 * 64 * 2048 * 2;
    int*   flag   = (int*)p2;
    float* Vts    = (float*)(p2 + 256);                           //    270,336 B
    bf16*  wp_cvt = (bf16*)(p2 + 256 + 32 * 33 * 64 * 4);         //  2,097,152 B
    float* Vtile  = (float*)((char*)wp_cvt + (size_t)CC * CC * 2);//    262,144 B

    // d_out scratch (dead-by-ordering): x_cvt/wa_cvt consumed by gemm1;
    // gemm2 is the only writer of d_out afterwards.
    bf16* x_cvt  = (bf16*)d_out;
    bf16* wa_cvt = (bf16*)d_out + (size_t)MT * CC;

    detect_dtype<<<1, 256, 0, stream>>>((const uint16_t*)x, flag);
    convert_all<<<(NX8 + NWA8 + NWP8) / 256, 256, 0, stream>>>(
        (const float*)x, (const float*)w_attn, (const float*)w_proj,
        x_cvt, wa_cvt, wp_cvt, flag);

    // gemm1: qkv projection. cols<2048 (Q,K) -> qk (ldc 2048);
    // cols>=2048 (V) -> Vt directly (sigma-packed layout).
    gemm_bt<<<dim3(C3 / 128, MT / 128), 256, 0, stream>>>(
        (const bf16*)x, x_cvt, (const bf16*)w_attn, wa_cvt, qk, Vt, flag,
        MT, C3, CC, CC, CC, /*ldc*/2048, /*split*/2048, /*cf32*/0);

    // V tile sums + suffix (soft-mask correction inputs)
    vtile2<<<dim3(32, BSZ * NH), 256, 0, stream>>>(Vt, Vtile);
    vts_suffix<<<dim3(BSZ * NH), dim3(64), 0, stream>>>(Vtile, Vts);

    // attention (XCD-swizzled flat grid, 128 q/block); y overwrites Q cols
    attn<<<dim3(512), 256, 0, stream>>>(qk, Vt, Vts);

    // gemm2: out = y @ w_proj^T  [4096, 1024] — 128x64 tiles
    gemm_bt64<<<dim3(CC / 64, MT / 128), 256, 0, stream>>>(
        qk, qk, (const bf16*)w_proj, wp_cvt, d_out, flag,
        MT, CC, CC, /*lda*/2048, CC, CC, /*cf32*/1);
}

// Round 2
// 196.683 us; speedup vs baseline: 1.0086x; 1.0086x over previous
//
#include <hip/hip_runtime.h>
#include <hip/hip_bf16.h>
#include <stdint.h>

// ---- problem constants (B=2, T=2048, C=1024, H=16, hs=64) ----
#define BSZ   2
#define TT    2048
#define NH    16
#define HS    64
#define CC    1024
#define C3    3072
#define MT    4096            // B*T rows
#define E10   4.5399929762484854e-05f   // exp(-10)
#define SCL2  0.1803368801111204f       // 0.125 * log2(e)

typedef __bf16 bf16;
typedef __bf16 bf16x8 __attribute__((ext_vector_type(8)));
typedef float  f32x4  __attribute__((ext_vector_type(4)));
typedef short  s16x4  __attribute__((ext_vector_type(4)));

#define AS1 __attribute__((address_space(1)))
#define AS3 __attribute__((address_space(3)))

__device__ __forceinline__ void glds16(const bf16* g, bf16* l) {
    __builtin_amdgcn_global_load_lds((const AS1 void*)g, (AS3 void*)l, 16, 0, 0);
}

// =====================================================================
// Input dtype detector: flag=0 -> bf16 inputs, flag=1 -> fp32 inputs.
// =====================================================================
__global__ void detect_dtype(const uint16_t* __restrict__ x, int* __restrict__ flag) {
    __shared__ int cnt;
    if (threadIdx.x == 0) cnt = 0;
    __syncthreads();
    int local = 0;
    for (int i = threadIdx.x; i < 512; i += 256) {
        uint16_t u = x[i];
        int e = (u >> 7) & 0xFF;
        if (e >= 96 && e <= 159) local++;
    }
    atomicAdd(&cnt, local);
    __syncthreads();
    if (threadIdx.x == 0) *flag = (cnt >= 461) ? 0 : 1;
}

// fused fp32->bf16 converts for x / w_attn / w_proj (no-op when flag==0)
#define NX8  (MT * CC / 8)          // 524288
#define NWA8 (C3 * CC / 8)          // 393216
#define NWP8 (CC * CC / 8)          // 131072
__global__ __launch_bounds__(256)
void convert_all(const float* __restrict__ x, const float* __restrict__ wa,
                 const float* __restrict__ wp, bf16* __restrict__ xd,
                 bf16* __restrict__ wad, bf16* __restrict__ wpd,
                 const int* __restrict__ flag) {
    if (*flag == 0) return;
    long i = (long)blockIdx.x * 256 + threadIdx.x;
    const float* s; bf16* d; long off;
    if (i < NX8)             { s = x;  d = xd;  off = i; }
    else if (i < NX8 + NWA8) { s = wa; d = wad; off = i - NX8; }
    else                     { s = wp; d = wpd; off = i - NX8 - NWA8; }
    const float4* sp = reinterpret_cast<const float4*>(s) + off * 2;
    float4 a = sp[0], b = sp[1];
    bf16x8 r;
    r[0] = (bf16)a.x; r[1] = (bf16)a.y; r[2] = (bf16)a.z; r[3] = (bf16)a.w;
    r[4] = (bf16)b.x; r[5] = (bf16)b.y; r[6] = (bf16)b.z; r[7] = (bf16)b.w;
    reinterpret_cast<bf16x8*>(d)[off] = r;
}

// =====================================================================
// GEMM 128x128: C = A*B^T, dbuf single-barrier pipeline. Split store:
// col-blocks >= split_col write V directly in Vt layout, now 32-key
// sigma packing: tloc = mi*16+quad*4+r -> pos = (mi>>1)*32 + quad*8 +
// (mi&1)*4 + r  (r contiguous, 8B packed store). Each 32-key half of a
// 64-tile is self-contained so attn can consume 32-key tiles.
// =====================================================================
__global__ __launch_bounds__(256)
void gemm_bt(const bf16* __restrict__ A0, const bf16* __restrict__ A1,
             const bf16* __restrict__ B0, const bf16* __restrict__ B1,
             void* __restrict__ Cmain, bf16* __restrict__ Cv,
             const int* __restrict__ flag,
             int M, int N, int K, int lda, int ldb, int ldc,
             int split_col, int cf32_dyn) {
    __shared__ bf16 As[2][128 * 32];
    __shared__ bf16 Bs[2][128 * 32];

    const int f = *flag;
    const bf16* A = f ? A1 : A0;
    const bf16* B = f ? B1 : B0;
    const int cf32 = cf32_dyn & f;

    const int tid  = threadIdx.x;
    const int lane = tid & 63;
    const int wave = tid >> 6;
    const int wm   = wave >> 1;
    const int wn   = wave & 1;
    const int quad = lane >> 4;
    const int l16  = lane & 15;

    const int row0 = blockIdx.y * 128;
    const int col0 = blockIdx.x * 128;

    const int srow = tid >> 2;
    const int skk  = (tid & 3) * 8;

    const bf16* Ap = A + (long)(row0 + srow) * lda + skk;
    const bf16* Bp = B + (long)(col0 + srow) * ldb + skk;

    auto stage = [&](int k0, int buf) {
        glds16(Ap + k0,                  &As[buf][wave * 512]);
        glds16(Ap + (long)64 * lda + k0, &As[buf][wave * 512 + 2048]);
        glds16(Bp + k0,                  &Bs[buf][wave * 512]);
        glds16(Bp + (long)64 * ldb + k0, &Bs[buf][wave * 512 + 2048]);
    };

    f32x4 acc[4][4] = {};
    stage(0, 0);

    for (int k0 = 0; k0 < K; k0 += 32) {
        const int buf = (k0 >> 5) & 1;
        __syncthreads();
        if (k0 + 32 < K) stage(k0 + 32, buf ^ 1);

        const bf16* Ac = As[buf];
        const bf16* Bc = Bs[buf];
        bf16x8 af[4], bfv[4];
#pragma unroll
        for (int mi = 0; mi < 4; ++mi)
            af[mi] = *reinterpret_cast<const bf16x8*>(&Ac[(wm * 64 + mi * 16 + l16) * 32 + quad * 8]);
#pragma unroll
        for (int ni = 0; ni < 4; ++ni)
            bfv[ni] = *reinterpret_cast<const bf16x8*>(&Bc[(wn * 64 + ni * 16 + l16) * 32 + quad * 8]);
#pragma unroll
        for (int mi = 0; mi < 4; ++mi)
#pragma unroll
            for (int ni = 0; ni < 4; ++ni)
                acc[mi][ni] = __builtin_amdgcn_mfma_f32_16x16x32_bf16(af[mi], bfv[ni], acc[mi][ni], 0, 0, 0);
    }

    if (split_col < 0 || col0 < split_col) {
        // main store (C/D layout: col=l16, row=quad*4+reg)
#pragma unroll
        for (int mi = 0; mi < 4; ++mi)
#pragma unroll
            for (int ni = 0; ni < 4; ++ni)
#pragma unroll
                for (int r = 0; r < 4; ++r) {
                    int row = row0 + wm * 64 + mi * 16 + quad * 4 + r;
                    int col = col0 + wn * 64 + ni * 16 + l16;
                    float v = acc[mi][ni][r];
                    if (cf32) ((float*)Cmain)[(long)row * ldc + col] = v;
                    else      ((bf16*)Cmain)[(long)row * ldc + col] = (bf16)v;
                }
    } else {
        // V store in Vt[bh][d][tc*64 + sigma32(tloc)] layout
        const int h  = (col0 - split_col + wn * 64) >> 6;   // wave-uniform
        const int bq = row0 >> 11;
        const int tc = ((row0 & 2047) >> 6) + wm;
#pragma unroll
        for (int ni = 0; ni < 4; ++ni) {
            long vrow = (long)(bq * NH + h) * 64 + ni * 16 + l16;
#pragma unroll
            for (int mi = 0; mi < 4; ++mi) {
                bf16 outv[4];
#pragma unroll
                for (int r = 0; r < 4; ++r) outv[r] = (bf16)acc[mi][ni][r];
                *reinterpret_cast<uint2*>(
                    &Cv[vrow * 2048 + tc * 64 + (mi >> 1) * 32 + quad * 8 + (mi & 1) * 4]) =
                    *reinterpret_cast<uint2*>(outv);
            }
        }
    }
}

// =====================================================================
// GEMM 128x64 (gemm2): grid 512 = 2 blocks/CU. acc[4][2].
// =====================================================================
__global__ __launch_bounds__(256)
void gemm_bt64(const bf16* __restrict__ A0, const bf16* __restrict__ A1,
               const bf16* __restrict__ B0, const bf16* __restrict__ B1,
               void* __restrict__ C, const int* __restrict__ flag,
               int M, int N, int K, int lda, int ldb, int ldc, int cf32_dyn) {
    __shared__ bf16 As[2][128 * 32];
    __shared__ bf16 Bs[2][64 * 32];

    const int f = *flag;
    const bf16* A = f ? A1 : A0;
    const bf16* B = f ? B1 : B0;
    const int cf32 = cf32_dyn & f;

    const int tid  = threadIdx.x;
    const int lane = tid & 63;
    const int wave = tid >> 6;
    const int wm   = wave >> 1;
    const int wn   = wave & 1;
    const int quad = lane >> 4;
    const int l16  = lane & 15;

    const int row0 = blockIdx.y * 128;
    const int col0 = blockIdx.x * 64;

    const int srow = tid >> 2;
    const int skk  = (tid & 3) * 8;

    const bf16* Ap = A + (long)(row0 + srow) * lda + skk;
    const bf16* Bp = B + (long)(col0 + srow) * ldb + skk;

    auto stage = [&](int k0, int buf) {
        glds16(Ap + k0,                  &As[buf][wave * 512]);
        glds16(Ap + (long)64 * lda + k0, &As[buf][wave * 512 + 2048]);
        glds16(Bp + k0,                  &Bs[buf][wave * 512]);
    };

    f32x4 acc[4][2] = {};
    stage(0, 0);

    for (int k0 = 0; k0 < K; k0 += 32) {
        const int buf = (k0 >> 5) & 1;
        __syncthreads();
        if (k0 + 32 < K) stage(k0 + 32, buf ^ 1);

        const bf16* Ac = As[buf];
        const bf16* Bc = Bs[buf];
        bf16x8 af[4], bfv[2];
#pragma unroll
        for (int mi = 0; mi < 4; ++mi)
            af[mi] = *reinterpret_cast<const bf16x8*>(&Ac[(wm * 64 + mi * 16 + l16) * 32 + quad * 8]);
#pragma unroll
        for (int ni = 0; ni < 2; ++ni)
            bfv[ni] = *reinterpret_cast<const bf16x8*>(&Bc[(wn * 32 + ni * 16 + l16) * 32 + quad * 8]);
#pragma unroll
        for (int mi = 0; mi < 4; ++mi)
#pragma unroll
            for (int ni = 0; ni < 2; ++ni)
                acc[mi][ni] = __builtin_amdgcn_mfma_f32_16x16x32_bf16(af[mi], bfv[ni], acc[mi][ni], 0, 0, 0);
    }

#pragma unroll
    for (int mi = 0; mi < 4; ++mi)
#pragma unroll
        for (int ni = 0; ni < 2; ++ni)
#pragma unroll
            for (int r = 0; r < 4; ++r) {
                int row = row0 + wm * 64 + mi * 16 + quad * 4 + r;
                int col = col0 + wn * 32 + ni * 16 + l16;
                float v = acc[mi][ni][r];
                if (cf32) ((float*)C)[(long)row * ldc + col] = v;
                else      ((bf16*)C)[(long)row * ldc + col] = (bf16)v;
            }
}

// =====================================================================
// Per-(bh,kt32) V half-tile sums from Vt rows (sigma32 permutes within
// each 32-key half -> half sums invariant). Grid (32 kt64, 32 bh).
// =====================================================================
__global__ __launch_bounds__(256)
void vtile2(const bf16* __restrict__ Vt, float* __restrict__ Vtile) {
    const int kt = blockIdx.x, bh = blockIdx.y;   // kt = 64-key tile
    const int tid = threadIdx.x;
    const int d = tid >> 2, part = tid & 3;       // part: 16-key quarter
    const bf16* p = Vt + ((long)bh * 64 + d) * 2048 + kt * 64 + part * 16;
    float s = 0.f;
#pragma unroll
    for (int i = 0; i < 2; ++i) {
        bf16x8 v = *reinterpret_cast<const bf16x8*>(p + i * 8);
#pragma unroll
        for (int j = 0; j < 8; ++j) s += (float)v[j];
    }
    s += __shfl_xor(s, 1, 64);                    // pair quarters -> halves
    if ((part & 1) == 0)
        Vtile[((long)bh * 64 + kt * 2 + (part >> 1)) * 64 + d] = s;
}

// Suffix over 64 x 32-key tiles (tiny).
__global__ void vts_suffix(const float* __restrict__ Vtile, float* __restrict__ Vts) {
    const int bh = blockIdx.x, d = threadIdx.x;
    Vts[((long)bh * 65 + 64) * 64 + d] = 0.f;
    float acc = 0.f;
    for (int kt = 63; kt >= 0; --kt) {
        acc += Vtile[((long)bh * 64 + kt) * 64 + d];
        Vts[((long)bh * 65 + kt) * 64 + d] = acc;
    }
}

// =====================================================================
// Flash attention v3: latency-oriented. 32 q-rows/block, 32-key tiles,
// 128 threads (2 waves x 16q), grid 2048 -> 8 independent blocks/CU,
// 16 waves/CU. Same transposed-compute fragment math as v1; K staged
// [32k][64d] with 8-chunk XOR swizzle, V staged [64d][32k] (sigma32
// columns) with 4-chunk XOR swizzle. Chunk ordering heavy-first with
// XCD-local bh; per-CU tile totals balanced within ~10%.
// =====================================================================
__global__ __launch_bounds__(128, 4)
void attn(bf16* __restrict__ qk, const bf16* __restrict__ Vt,
          const float* __restrict__ Vts) {
    __shared__ bf16 Ks[2][32 * 64];
    __shared__ bf16 Vs[2][64 * 32];

    const int tid  = threadIdx.x;
    const int lane = tid & 63;
    const int wave = tid >> 6;              // 0..1
    const int quad = lane >> 4;
    const int l16  = lane & 15;

    const int f2   = blockIdx.x;            // 0..2047
    const int xcd  = f2 & 7;
    const int slot = f2 >> 3;               // 0..255
    const int bh   = (slot & 3) * 8 + xcd;
    const int chunk = 63 - (slot >> 2);     // 0..63, heavy first
    const int b = bh >> 4, h = bh & 15;
    const int q0 = chunk * 32;
    const long rbase = (long)b * TT;
    const int ktend = chunk + 1;            // 32-key tiles

    const bf16* qp = qk + (rbase + q0 + wave * 16 + l16) * 2048 + h * HS;
    bf16x8 qf0 = *reinterpret_cast<const bf16x8*>(qp + quad * 8);
    bf16x8 qf1 = *reinterpret_cast<const bf16x8*>(qp + 32 + quad * 8);

    f32x4 O[4] = {};
    float lp = 0.f;

    // K staging: rows = keys (32 x 128B), 8-row stripes, 8 chunks/row
    const int rl  = lane >> 3;              // 0..7
    const int cs  = (lane & 7) ^ rl;
    const bf16* kgb = qk + (rbase + wave * 16 + rl) * 2048 + CC + h * HS + cs * 8;
    // V staging: rows = d (64 x 64B), 4 chunks/row
    const int rlv = lane >> 2;              // 0..15
    const int csv = (lane & 3) ^ (rlv & 3);
    const bf16* vgb = Vt + ((long)(b * NH + h) * 64 + wave * 32 + rlv) * 2048 + csv * 8;

    const int sx = l16 & 7;
    const int sv = l16 & 3;

    auto stage = [&](int kt, int buf) {
        glds16(kgb + (long)(kt * 32) * 2048,     &Ks[buf][wave * 1024]);
        glds16(kgb + (long)(kt * 32 + 8) * 2048, &Ks[buf][wave * 1024 + 512]);
        glds16(vgb + kt * 32,                    &Vs[buf][wave * 1024]);
        glds16(vgb + (long)16 * 2048 + kt * 32,  &Vs[buf][wave * 1024 + 512]);
    };

    stage(0, 0);

    for (int kt = 0; kt < ktend; ++kt) {
        const int buf = kt & 1;
        __syncthreads();
        if (kt + 1 < ktend) stage(kt + 1, buf ^ 1);

        const bf16* Kc = Ks[buf];
        const bf16* Vc = Vs[buf];

        bf16x8 kf0[2], kf1[2];
#pragma unroll
        for (int gg = 0; gg < 2; ++gg) {
            const int krow = gg * 16 + l16;
            kf0[gg] = *reinterpret_cast<const bf16x8*>(&Kc[krow * 64 + ((quad ^ sx) * 8)]);
            kf1[gg] = *reinterpret_cast<const bf16x8*>(&Kc[krow * 64 + (((4 + quad) ^ sx) * 8)]);
        }
        s16x4 vf[4][2];
#pragma unroll
        for (int dg = 0; dg < 4; ++dg) {
            const int vrow = dg * 16 + l16;
            union { uint4 u; s16x4 s[2]; } ua;
            ua.u = *reinterpret_cast<const uint4*>(&Vc[vrow * 32 + ((quad ^ sv) * 8)]);
            vf[dg][0] = ua.s[0]; vf[dg][1] = ua.s[1];
        }

        f32x4 S[2] = {};
#pragma unroll
        for (int gg = 0; gg < 2; ++gg) {
            S[gg] = __builtin_amdgcn_mfma_f32_16x16x32_bf16(kf0[gg], qf0, S[gg], 0, 0, 0);
            S[gg] = __builtin_amdgcn_mfma_f32_16x16x32_bf16(kf1[gg], qf1, S[gg], 0, 0, 0);
        }

        const bool dtile = (kt == ktend - 1);
        const int ql = wave * 16 + l16;
        s16x4 pk[2];
#pragma unroll
        for (int gg = 0; gg < 2; ++gg) {
#pragma unroll
            for (int r = 0; r < 4; ++r) {
                float p = __builtin_exp2f(S[gg][r] * SCL2);
                if (dtile) {
                    int kl = gg * 16 + quad * 4 + r;
                    p = (kl > ql) ? E10 : p;
                }
                lp += p;
                union { bf16 b_; short s_; } u;
                u.b_ = (bf16)p;
                pk[gg][r] = u.s_;
            }
        }

#pragma unroll
        for (int dg = 0; dg < 4; ++dg) {
            O[dg] = __builtin_amdgcn_mfma_f32_16x16x16bf16_1k(vf[dg][0], pk[0], O[dg], 0, 0, 0);
            O[dg] = __builtin_amdgcn_mfma_f32_16x16x16bf16_1k(vf[dg][1], pk[1], O[dg], 0, 0, 0);
        }
    }

    lp += __shfl_xor(lp, 16, 64);
    lp += __shfl_xor(lp, 32, 64);

    const int nfut = TT - ktend * 32;
    const float l = lp + (float)nfut * E10;
    const float invl = 1.0f / l;
    const float* vfp = Vts + ((long)bh * 65 + ktend) * 64;

    bf16* yp = qk + (rbase + q0 + wave * 16 + l16) * 2048 + h * HS;
#pragma unroll
    for (int dg = 0; dg < 4; ++dg) {
        bf16 outv[4];
#pragma unroll
        for (int r = 0; r < 4; ++r) {
            float o = O[dg][r] + E10 * vfp[dg * 16 + quad * 4 + r];
            outv[r] = (bf16)(o * invl);
        }
        *reinterpret_cast<uint2*>(yp + dg * 16 + quad * 4) =
            *reinterpret_cast<uint2*>(outv);
    }
}

// =====================================================================
extern "C" void kernel_launch(void* const* d_in, const int* in_sizes, int n_in,
                              void* d_out, int out_size, void* d_ws, size_t ws_size,
                              hipStream_t stream) {
    const void* x      = d_in[0];
    const void* w_attn = d_in[1];
    const void* w_proj = d_in[2];

    // ws (~28 MB): qk | Vt | flag | Vts | wp_cvt | Vtile
    char* ws = (char*)d_ws;
    bf16*  qk     = (bf16*)ws;                                    // 16,777,216 B
    bf16*  Vt     = (bf16*)(ws + (size_t)MT * 2048 * 2);          //  8,388,608 B
    char*  p2     = ws + (size_t)MT * 2048 * 2 + (size_t)32 * 64 * 2048 * 2;
    int*   flag   = (int*)p2;
    float* Vts    = (float*)(p2 + 256);                           //    532,480 B (32*65*64*4)
    bf16*  wp_cvt = (bf16*)(p2 + 256 + 32 * 65 * 64 * 4);         //  2,097,152 B
    float* Vtile  = (float*)((char*)wp_cvt + (size_t)CC * CC * 2);//    524,288 B (32*64*64*4)

    // d_out scratch (dead-by-ordering): x_cvt/wa_cvt consumed by gemm1;
    // gemm2 is the only writer of d_out afterwards.
    bf16* x_cvt  = (bf16*)d_out;
    bf16* wa_cvt = (bf16*)d_out + (size_t)MT * CC;

    detect_dtype<<<1, 256, 0, stream>>>((const uint16_t*)x, flag);
    convert_all<<<(NX8 + NWA8 + NWP8) / 256, 256, 0, stream>>>(
        (const float*)x, (const float*)w_attn, (const float*)w_proj,
        x_cvt, wa_cvt, wp_cvt, flag);

    // gemm1: qkv projection. cols<2048 (Q,K) -> qk (ldc 2048);
    // cols>=2048 (V) -> Vt directly (sigma32-packed layout).
    gemm_bt<<<dim3(C3 / 128, MT / 128), 256, 0, stream>>>(
        (const bf16*)x, x_cvt, (const bf16*)w_attn, wa_cvt, qk, Vt, flag,
        MT, C3, CC, CC, CC, /*ldc*/2048, /*split*/2048, /*cf32*/0);

    // V tile sums + suffix (soft-mask correction inputs), 32-key grain
    vtile2<<<dim3(32, BSZ * NH), 256, 0, stream>>>(Vt, Vtile);
    vts_suffix<<<dim3(BSZ * NH), dim3(64), 0, stream>>>(Vtile, Vts);

    // attention: 2048 blocks x 128 threads (8 blocks/CU), 32q/32k tiles
    attn<<<dim3(2048), 128, 0, stream>>>(qk, Vt, Vts);

    // gemm2: out = y @ w_proj^T  [4096, 1024] — 128x64 tiles
    gemm_bt64<<<dim3(CC / 64, MT / 128), 256, 0, stream>>>(
        qk, qk, (const bf16*)w_proj, wp_cvt, d_out, flag,
        MT, CC, CC, /*lda*/2048, CC, CC, /*cf32*/1);
}

// Round 3
// 185.706 us; speedup vs baseline: 1.0682x; 1.0591x over previous
//
#include <hip/hip_runtime.h>
#include <hip/hip_bf16.h>
#include <stdint.h>

// ---- problem constants (B=2, T=2048, C=1024, H=16, hs=64) ----
#define BSZ   2
#define TT    2048
#define NH    16
#define HS    64
#define CC    1024
#define C3    3072
#define MT    4096            // B*T rows
#define E10   4.5399929762484854e-05f   // exp(-10)
#define SCL2  0.1803368801111204f       // 0.125 * log2(e)

typedef __bf16 bf16;
typedef __bf16 bf16x8 __attribute__((ext_vector_type(8)));
typedef float  f32x4  __attribute__((ext_vector_type(4)));
typedef short  s16x4  __attribute__((ext_vector_type(4)));

#define AS1 __attribute__((address_space(1)))
#define AS3 __attribute__((address_space(3)))

__device__ __forceinline__ void glds16(const bf16* g, bf16* l) {
    __builtin_amdgcn_global_load_lds((const AS1 void*)g, (AS3 void*)l, 16, 0, 0);
}

// =====================================================================
// Input dtype detector: flag=0 -> bf16 inputs, flag=1 -> fp32 inputs.
// =====================================================================
__global__ void detect_dtype(const uint16_t* __restrict__ x, int* __restrict__ flag) {
    __shared__ int cnt;
    if (threadIdx.x == 0) cnt = 0;
    __syncthreads();
    int local = 0;
    for (int i = threadIdx.x; i < 512; i += 256) {
        uint16_t u = x[i];
        int e = (u >> 7) & 0xFF;
        if (e >= 96 && e <= 159) local++;
    }
    atomicAdd(&cnt, local);
    __syncthreads();
    if (threadIdx.x == 0) *flag = (cnt >= 461) ? 0 : 1;
}

// fused fp32->bf16 converts for x / w_attn / w_proj (no-op when flag==0)
#define NX8  (MT * CC / 8)          // 524288
#define NWA8 (C3 * CC / 8)          // 393216
#define NWP8 (CC * CC / 8)          // 131072
__global__ __launch_bounds__(256)
void convert_all(const float* __restrict__ x, const float* __restrict__ wa,
                 const float* __restrict__ wp, bf16* __restrict__ xd,
                 bf16* __restrict__ wad, bf16* __restrict__ wpd,
                 const int* __restrict__ flag) {
    if (*flag == 0) return;
    long i = (long)blockIdx.x * 256 + threadIdx.x;
    const float* s; bf16* d; long off;
    if (i < NX8)             { s = x;  d = xd;  off = i; }
    else if (i < NX8 + NWA8) { s = wa; d = wad; off = i - NX8; }
    else                     { s = wp; d = wpd; off = i - NX8 - NWA8; }
    const float4* sp = reinterpret_cast<const float4*>(s) + off * 2;
    float4 a = sp[0], b = sp[1];
    bf16x8 r;
    r[0] = (bf16)a.x; r[1] = (bf16)a.y; r[2] = (bf16)a.z; r[3] = (bf16)a.w;
    r[4] = (bf16)b.x; r[5] = (bf16)b.y; r[6] = (bf16)b.z; r[7] = (bf16)b.w;
    reinterpret_cast<bf16x8*>(d)[off] = r;
}

// =====================================================================
// GEMM 128x128: C = A*B^T, dbuf single-barrier pipeline. Split store:
// col-blocks >= split_col write V directly in Vt layout (sigma-packed):
// tloc = mi*16+quad*4+r -> sigma(tloc) = quad*16+mi*4+r (r contiguous,
// 8B packed store). Kills the separate vtranspose pass.
// =====================================================================
__global__ __launch_bounds__(256)
void gemm_bt(const bf16* __restrict__ A0, const bf16* __restrict__ A1,
             const bf16* __restrict__ B0, const bf16* __restrict__ B1,
             void* __restrict__ Cmain, bf16* __restrict__ Cv,
             const int* __restrict__ flag,
             int M, int N, int K, int lda, int ldb, int ldc,
             int split_col, int cf32_dyn) {
    __shared__ bf16 As[2][128 * 32];
    __shared__ bf16 Bs[2][128 * 32];

    const int f = *flag;
    const bf16* A = f ? A1 : A0;
    const bf16* B = f ? B1 : B0;
    const int cf32 = cf32_dyn & f;

    const int tid  = threadIdx.x;
    const int lane = tid & 63;
    const int wave = tid >> 6;
    const int wm   = wave >> 1;
    const int wn   = wave & 1;
    const int quad = lane >> 4;
    const int l16  = lane & 15;

    const int row0 = blockIdx.y * 128;
    const int col0 = blockIdx.x * 128;

    const int srow = tid >> 2;
    const int skk  = (tid & 3) * 8;

    const bf16* Ap = A + (long)(row0 + srow) * lda + skk;
    const bf16* Bp = B + (long)(col0 + srow) * ldb + skk;

    auto stage = [&](int k0, int buf) {
        glds16(Ap + k0,                  &As[buf][wave * 512]);
        glds16(Ap + (long)64 * lda + k0, &As[buf][wave * 512 + 2048]);
        glds16(Bp + k0,                  &Bs[buf][wave * 512]);
        glds16(Bp + (long)64 * ldb + k0, &Bs[buf][wave * 512 + 2048]);
    };

    f32x4 acc[4][4] = {};
    stage(0, 0);

    for (int k0 = 0; k0 < K; k0 += 32) {
        const int buf = (k0 >> 5) & 1;
        __syncthreads();
        if (k0 + 32 < K) stage(k0 + 32, buf ^ 1);

        const bf16* Ac = As[buf];
        const bf16* Bc = Bs[buf];
        bf16x8 af[4], bfv[4];
#pragma unroll
        for (int mi = 0; mi < 4; ++mi)
            af[mi] = *reinterpret_cast<const bf16x8*>(&Ac[(wm * 64 + mi * 16 + l16) * 32 + quad * 8]);
#pragma unroll
        for (int ni = 0; ni < 4; ++ni)
            bfv[ni] = *reinterpret_cast<const bf16x8*>(&Bc[(wn * 64 + ni * 16 + l16) * 32 + quad * 8]);
#pragma unroll
        for (int mi = 0; mi < 4; ++mi)
#pragma unroll
            for (int ni = 0; ni < 4; ++ni)
                acc[mi][ni] = __builtin_amdgcn_mfma_f32_16x16x32_bf16(af[mi], bfv[ni], acc[mi][ni], 0, 0, 0);
    }

    if (split_col < 0 || col0 < split_col) {
        // main store (C/D layout: col=l16, row=quad*4+reg)
#pragma unroll
        for (int mi = 0; mi < 4; ++mi)
#pragma unroll
            for (int ni = 0; ni < 4; ++ni)
#pragma unroll
                for (int r = 0; r < 4; ++r) {
                    int row = row0 + wm * 64 + mi * 16 + quad * 4 + r;
                    int col = col0 + wn * 64 + ni * 16 + l16;
                    float v = acc[mi][ni][r];
                    if (cf32) ((float*)Cmain)[(long)row * ldc + col] = v;
                    else      ((bf16*)Cmain)[(long)row * ldc + col] = (bf16)v;
                }
    } else {
        // V store in Vt[bh][d][tc*64 + sigma(tloc)] layout
        const int h  = (col0 - split_col + wn * 64) >> 6;   // wave-uniform
        const int bq = row0 >> 11;
        const int tc = ((row0 & 2047) >> 6) + wm;
#pragma unroll
        for (int ni = 0; ni < 4; ++ni) {
            long vrow = (long)(bq * NH + h) * 64 + ni * 16 + l16;
#pragma unroll
            for (int mi = 0; mi < 4; ++mi) {
                bf16 outv[4];
#pragma unroll
                for (int r = 0; r < 4; ++r) outv[r] = (bf16)acc[mi][ni][r];
                *reinterpret_cast<uint2*>(&Cv[vrow * 2048 + tc * 64 + quad * 16 + mi * 4]) =
                    *reinterpret_cast<uint2*>(outv);
            }
        }
    }
}

// =====================================================================
// GEMM 128x64 (gemm2): grid 512 = 2 blocks/CU. acc[4][2].
// =====================================================================
__global__ __launch_bounds__(256)
void gemm_bt64(const bf16* __restrict__ A0, const bf16* __restrict__ A1,
               const bf16* __restrict__ B0, const bf16* __restrict__ B1,
               void* __restrict__ C, const int* __restrict__ flag,
               int M, int N, int K, int lda, int ldb, int ldc, int cf32_dyn) {
    __shared__ bf16 As[2][128 * 32];
    __shared__ bf16 Bs[2][64 * 32];

    const int f = *flag;
    const bf16* A = f ? A1 : A0;
    const bf16* B = f ? B1 : B0;
    const int cf32 = cf32_dyn & f;

    const int tid  = threadIdx.x;
    const int lane = tid & 63;
    const int wave = tid >> 6;
    const int wm   = wave >> 1;
    const int wn   = wave & 1;
    const int quad = lane >> 4;
    const int l16  = lane & 15;

    const int row0 = blockIdx.y * 128;
    const int col0 = blockIdx.x * 64;

    const int srow = tid >> 2;
    const int skk  = (tid & 3) * 8;

    const bf16* Ap = A + (long)(row0 + srow) * lda + skk;
    const bf16* Bp = B + (long)(col0 + srow) * ldb + skk;

    auto stage = [&](int k0, int buf) {
        glds16(Ap + k0,                  &As[buf][wave * 512]);
        glds16(Ap + (long)64 * lda + k0, &As[buf][wave * 512 + 2048]);
        glds16(Bp + k0,                  &Bs[buf][wave * 512]);
    };

    f32x4 acc[4][2] = {};
    stage(0, 0);

    for (int k0 = 0; k0 < K; k0 += 32) {
        const int buf = (k0 >> 5) & 1;
        __syncthreads();
        if (k0 + 32 < K) stage(k0 + 32, buf ^ 1);

        const bf16* Ac = As[buf];
        const bf16* Bc = Bs[buf];
        bf16x8 af[4], bfv[2];
#pragma unroll
        for (int mi = 0; mi < 4; ++mi)
            af[mi] = *reinterpret_cast<const bf16x8*>(&Ac[(wm * 64 + mi * 16 + l16) * 32 + quad * 8]);
#pragma unroll
        for (int ni = 0; ni < 2; ++ni)
            bfv[ni] = *reinterpret_cast<const bf16x8*>(&Bc[(wn * 32 + ni * 16 + l16) * 32 + quad * 8]);
#pragma unroll
        for (int mi = 0; mi < 4; ++mi)
#pragma unroll
            for (int ni = 0; ni < 2; ++ni)
                acc[mi][ni] = __builtin_amdgcn_mfma_f32_16x16x32_bf16(af[mi], bfv[ni], acc[mi][ni], 0, 0, 0);
    }

#pragma unroll
    for (int mi = 0; mi < 4; ++mi)
#pragma unroll
        for (int ni = 0; ni < 2; ++ni)
#pragma unroll
            for (int r = 0; r < 4; ++r) {
                int row = row0 + wm * 64 + mi * 16 + quad * 4 + r;
                int col = col0 + wn * 32 + ni * 16 + l16;
                float v = acc[mi][ni][r];
                if (cf32) ((float*)C)[(long)row * ldc + col] = v;
                else      ((bf16*)C)[(long)row * ldc + col] = (bf16)v;
            }
}

// =====================================================================
// Per-(bh,kt) V tile sums from Vt rows (sigma permutes within a tile ->
// sum invariant). 1024 blocks, coalesced 32B/thread.
// =====================================================================
__global__ __launch_bounds__(256)
void vtile2(const bf16* __restrict__ Vt, float* __restrict__ Vtile) {
    const int kt = blockIdx.x, bh = blockIdx.y;
    const int tid = threadIdx.x;
    const int d = tid >> 2, part = tid & 3;
    const bf16* p = Vt + ((long)bh * 64 + d) * 2048 + kt * 64 + part * 16;
    float s = 0.f;
#pragma unroll
    for (int i = 0; i < 2; ++i) {
        bf16x8 v = *reinterpret_cast<const bf16x8*>(p + i * 8);
#pragma unroll
        for (int j = 0; j < 8; ++j) s += (float)v[j];
    }
    s += __shfl_xor(s, 1, 64);
    s += __shfl_xor(s, 2, 64);
    if (part == 0) Vtile[((long)bh * 32 + kt) * 64 + d] = s;
}

// Suffix over 64-key tiles (tiny).
__global__ void vts_suffix(const float* __restrict__ Vtile, float* __restrict__ Vts) {
    const int bh = blockIdx.x, d = threadIdx.x;
    Vts[((long)bh * 33 + 32) * 64 + d] = 0.f;
    float acc = 0.f;
    for (int kt = 31; kt >= 0; --kt) {
        acc += Vtile[((long)bh * 32 + kt) * 64 + d];
        Vts[((long)bh * 33 + kt) * 64 + d] = acc;
    }
}

// =====================================================================
// Flash attention v4: v1 structure (64q x 64k, 4 waves, 1024 blocks)
// + depth-2 counted-vmcnt prefetch (3 LDS buffers, raw s_barrier,
//   vmcnt(4) instead of the compiler's vmcnt(0) barrier drain)
// + producer-aligned XCD mapping: gemm1 writes head h's Q/K/V slices
//   from XCD h>>1 (grid 24x32: xcd = bx%8), so map attn blocks with
//   xcd = h>>1 -> all staging reads are XCD-local L2 hits.
// =====================================================================
__global__ __launch_bounds__(256, 3)
void attn(bf16* __restrict__ qk, const bf16* __restrict__ Vt,
          const float* __restrict__ Vts) {
    __shared__ bf16 Ks[3][64 * 64];
    __shared__ bf16 Vs[3][64 * 64];

    const int tid  = threadIdx.x;
    const int lane = tid & 63;
    const int wave = tid >> 6;
    const int quad = lane >> 4;
    const int l16  = lane & 15;

    const int f2   = blockIdx.x;            // 0..1023
    const int xcd  = f2 & 7;
    const int slot = f2 >> 3;               // 0..127
    const int u    = slot & 3;              // {b, h&1}
    const int chunk = 31 - (slot >> 2);     // heavy first
    const int h = xcd * 2 + (u & 1);        // head's producer XCD = h>>1
    const int b = u >> 1;
    const int bh = b * 16 + h;
    const int q0 = chunk * 64;
    const long rbase = (long)b * TT;
    const int ktend = chunk + 1;

    const bf16* qp = qk + (rbase + q0 + wave * 16 + l16) * 2048 + h * HS;
    bf16x8 qf0 = *reinterpret_cast<const bf16x8*>(qp + quad * 8);
    bf16x8 qf1 = *reinterpret_cast<const bf16x8*>(qp + 32 + quad * 8);

    f32x4 O[4] = {};
    float lp = 0.f;

    const int rl  = lane >> 3;
    const int cs  = (lane & 7) ^ rl;
    const int row0dma = wave * 16 + rl;
    const bf16* kgb = qk + (rbase + row0dma) * 2048 + CC + h * HS + cs * 8;
    const bf16* vgb = Vt + ((long)(b * NH + h) * 64 + row0dma) * 2048 + cs * 8;
    const int sx = l16 & 7;

    auto stage = [&](int kt, int buf) {
        glds16(kgb + (long)(kt * 64) * 2048,     &Ks[buf][wave * 1024]);
        glds16(kgb + (long)(kt * 64 + 8) * 2048, &Ks[buf][wave * 1024 + 512]);
        glds16(vgb + kt * 64,                    &Vs[buf][wave * 1024]);
        glds16(vgb + 8 * 2048 + kt * 64,         &Vs[buf][wave * 1024 + 512]);
    };

    // depth-2 prefetch prologue (clamped indices keep vmcnt uniform)
    stage(0, 0);
    stage(ktend > 1 ? 1 : 0, 1);

    int rb = 0;                 // read buffer  = kt % 3
    int sb = 2;                 // stage buffer = (kt+2) % 3
    for (int kt = 0; kt < ktend; ++kt) {
        // tile kt's 4 loads were issued 2 iters ago; only the newer 8
        // (tiles kt+1, kt+2) may remain outstanding after this wait.
        asm volatile("s_waitcnt vmcnt(4)" ::: "memory");
        __builtin_amdgcn_s_barrier();
        __builtin_amdgcn_sched_barrier(0);

        int nkt = kt + 2; nkt = (nkt < ktend) ? nkt : (ktend - 1);
        stage(nkt, sb);

        const bf16* Kc = Ks[rb];
        const bf16* Vc = Vs[rb];

        bf16x8 kf0[4], kf1[4];
#pragma unroll
        for (int g = 0; g < 4; ++g) {
            const int krow = g * 16 + l16;
            kf0[g] = *reinterpret_cast<const bf16x8*>(&Kc[krow * 64 + ((quad ^ sx) * 8)]);
            kf1[g] = *reinterpret_cast<const bf16x8*>(&Kc[krow * 64 + (((4 + quad) ^ sx) * 8)]);
        }
        s16x4 vf[4][4];
#pragma unroll
        for (int dg = 0; dg < 4; ++dg) {
            const int vrow = dg * 16 + l16;
            union { uint4 u; s16x4 s[2]; } ua, ub;
            ua.u = *reinterpret_cast<const uint4*>(&Vc[vrow * 64 + (((2 * quad) ^ sx) * 8)]);
            ub.u = *reinterpret_cast<const uint4*>(&Vc[vrow * 64 + (((2 * quad + 1) ^ sx) * 8)]);
            vf[dg][0] = ua.s[0]; vf[dg][1] = ua.s[1];
            vf[dg][2] = ub.s[0]; vf[dg][3] = ub.s[1];
        }

        f32x4 S[4] = {};
        __builtin_amdgcn_s_setprio(1);
#pragma unroll
        for (int g = 0; g < 4; ++g) {
            S[g] = __builtin_amdgcn_mfma_f32_16x16x32_bf16(kf0[g], qf0, S[g], 0, 0, 0);
            S[g] = __builtin_amdgcn_mfma_f32_16x16x32_bf16(kf1[g], qf1, S[g], 0, 0, 0);
        }
        __builtin_amdgcn_s_setprio(0);

        const bool dtile = (kt == ktend - 1);
        const int ql = wave * 16 + l16;
        s16x4 pk[4];
#pragma unroll
        for (int g = 0; g < 4; ++g) {
#pragma unroll
            for (int r = 0; r < 4; ++r) {
                float p = __builtin_exp2f(S[g][r] * SCL2);
                if (dtile) {
                    int kl = g * 16 + quad * 4 + r;
                    p = (kl > ql) ? E10 : p;
                }
                lp += p;
                union { bf16 b_; short s_; } u2;
                u2.b_ = (bf16)p;
                pk[g][r] = u2.s_;
            }
        }

        __builtin_amdgcn_s_setprio(1);
#pragma unroll
        for (int dg = 0; dg < 4; ++dg) {
            O[dg] = __builtin_amdgcn_mfma_f32_16x16x16bf16_1k(vf[dg][0], pk[0], O[dg], 0, 0, 0);
            O[dg] = __builtin_amdgcn_mfma_f32_16x16x16bf16_1k(vf[dg][1], pk[1], O[dg], 0, 0, 0);
            O[dg] = __builtin_amdgcn_mfma_f32_16x16x16bf16_1k(vf[dg][2], pk[2], O[dg], 0, 0, 0);
            O[dg] = __builtin_amdgcn_mfma_f32_16x16x16bf16_1k(vf[dg][3], pk[3], O[dg], 0, 0, 0);
        }
        __builtin_amdgcn_s_setprio(0);

        rb = (rb == 2) ? 0 : rb + 1;
        sb = (sb == 2) ? 0 : sb + 1;
    }

    lp += __shfl_xor(lp, 16, 64);
    lp += __shfl_xor(lp, 32, 64);

    const int nfut = TT - ktend * 64;
    const float l = lp + (float)nfut * E10;
    const float invl = 1.0f / l;
    const float* vfp = Vts + ((long)bh * 33 + ktend) * 64;

    bf16* yp = qk + (rbase + q0 + wave * 16 + l16) * 2048 + h * HS;
#pragma unroll
    for (int dg = 0; dg < 4; ++dg) {
        bf16 outv[4];
#pragma unroll
        for (int r = 0; r < 4; ++r) {
            float o = O[dg][r] + E10 * vfp[dg * 16 + quad * 4 + r];
            outv[r] = (bf16)(o * invl);
        }
        *reinterpret_cast<uint2*>(yp + dg * 16 + quad * 4) =
            *reinterpret_cast<uint2*>(outv);
    }
}

// =====================================================================
extern "C" void kernel_launch(void* const* d_in, const int* in_sizes, int n_in,
                              void* d_out, int out_size, void* d_ws, size_t ws_size,
                              hipStream_t stream) {
    const void* x      = d_in[0];
    const void* w_attn = d_in[1];
    const void* w_proj = d_in[2];

    // ws (~27.8 MB): qk | Vt | flag | Vts | wp_cvt | Vtile
    char* ws = (char*)d_ws;
    bf16*  qk     = (bf16*)ws;                                    // 16,777,216 B
    bf16*  Vt     = (bf16*)(ws + (size_t)MT * 2048 * 2);          //  8,388,608 B
    char*  p2     = ws + (size_t)MT * 2048 * 2 + (size_t)32 * 64 * 2048 * 2;
    int*   flag   = (int*)p2;
    float* Vts    = (float*)(p2 + 256);                           //    270,336 B
    bf16*  wp_cvt = (bf16*)(p2 + 256 + 32 * 33 * 64 * 4);         //  2,097,152 B
    float* Vtile  = (float*)((char*)wp_cvt + (size_t)CC * CC * 2);//    262,144 B

    // d_out scratch (dead-by-ordering): x_cvt/wa_cvt consumed by gemm1;
    // gemm2 is the only writer of d_out afterwards.
    bf16* x_cvt  = (bf16*)d_out;
    bf16* wa_cvt = (bf16*)d_out + (size_t)MT * CC;

    detect_dtype<<<1, 256, 0, stream>>>((const uint16_t*)x, flag);
    convert_all<<<(NX8 + NWA8 + NWP8) / 256, 256, 0, stream>>>(
        (const float*)x, (const float*)w_attn, (const float*)w_proj,
        x_cvt, wa_cvt, wp_cvt, flag);

    // gemm1: qkv projection. cols<2048 (Q,K) -> qk (ldc 2048);
    // cols>=2048 (V) -> Vt directly (sigma-packed layout).
    gemm_bt<<<dim3(C3 / 128, MT / 128), 256, 0, stream>>>(
        (const bf16*)x, x_cvt, (const bf16*)w_attn, wa_cvt, qk, Vt, flag,
        MT, C3, CC, CC, CC, /*ldc*/2048, /*split*/2048, /*cf32*/0);

    // V tile sums + suffix (soft-mask correction inputs)
    vtile2<<<dim3(32, BSZ * NH), 256, 0, stream>>>(Vt, Vtile);
    vts_suffix<<<dim3(BSZ * NH), dim3(64), 0, stream>>>(Vtile, Vts);

    // attention (producer-XCD-aligned grid); y overwrites Q columns of qk
    attn<<<dim3(1024), 256, 0, stream>>>(qk, Vt, Vts);

    // gemm2: out = y @ w_proj^T  [4096, 1024] — 128x64 tiles
    gemm_bt64<<<dim3(CC / 64, MT / 128), 256, 0, stream>>>(
        qk, qk, (const bf16*)w_proj, wp_cvt, d_out, flag,
        MT, CC, CC, /*lda*/2048, CC, CC, /*cf32*/1);
}